// Round 9
// baseline (135.489 us; speedup 1.0000x reference)
//
#include <hip/hip_runtime.h>

static constexpr int    N      = 2048;
static constexpr int    NBLK   = 256;
static constexpr int    NTHR   = 1024;
static constexpr int    RPB    = 8;     // rows (and cols) per block
static constexpr double D_MASS = 0.9;
static constexpr double D_TOL  = 0.01;
static constexpr int    NITER  = 50;

typedef _Float16 half4_t __attribute__((ext_vector_type(4)));
typedef _Float16 half2_t __attribute__((ext_vector_type(2)));

struct Ws {
    unsigned flagS[NBLK], flagV[NBLK];   // per-block epoch flags (zeroed per call)
    unsigned gateS, gateV;               // master gates
    unsigned cntP, cntV, cntE, _pad;     // fallback counters
    double bandSum[NBLK], s2Band[NBLK];
    double rowSum[N];
    double dotParts[NBLK], errAParts[NBLK], errBParts[NBLK];
    double errParts[NBLK];               // fallback err partials
    float  V[N], Vp[N];
    float  partialT[(size_t)N * NBLK];   // fallback only, [col][srcblk]
};

__global__ void init_sync(Ws* ws) {
    const int t = threadIdx.x;           // 256
    ws->flagS[t] = 0u; ws->flagV[t] = 0u;
    if (t == 0) { ws->gateS = 0u; ws->gateV = 0u;
                  ws->cntP = 0u; ws->cntV = 0u; ws->cntE = 0u; }
}

// deterministic all-thread block reduction (1024 threads, 16 waves)
__device__ __forceinline__ double block_reduce(double v, double* s16) {
    for (int off = 32; off; off >>= 1) v += __shfl_xor(v, off, 64);
    const int wave = threadIdx.x >> 6, lane = threadIdx.x & 63;
    __syncthreads();
    if (lane == 0) s16[wave] = v;
    __syncthreads();
    double s = 0.0;
    #pragma unroll
    for (int w = 0; w < 16; ++w) s += s16[w];
    return s;
}

// ---- cheap global rendezvous: parallel release flags, 1 aggregator, 1 gate ----
__device__ __forceinline__ void arrive_flag(unsigned* slot, unsigned epoch) {
    __syncthreads();   // block's prior stores drained before release
    if (threadIdx.x == 0)
        __hip_atomic_store(slot, epoch, __ATOMIC_RELEASE, __HIP_MEMORY_SCOPE_AGENT);
}
__device__ __forceinline__ void gate_rendezvous(unsigned* flags, unsigned* gate,
                                                unsigned epoch) {
    if (blockIdx.x == 0 && threadIdx.x < 64) {   // aggregator wave
        const int l = threadIdx.x;
        for (;;) {
            bool ok = true;
            #pragma unroll
            for (int q = 0; q < 4; ++q)
                ok &= (__hip_atomic_load(flags + 4 * l + q, __ATOMIC_RELAXED,
                                         __HIP_MEMORY_SCOPE_AGENT) >= epoch);
            if (__all((int)ok)) break;
            __builtin_amdgcn_s_sleep(1);
        }
        __builtin_amdgcn_fence(__ATOMIC_ACQUIRE, "agent");
        if (l == 0)
            __hip_atomic_store(gate, epoch, __ATOMIC_RELEASE, __HIP_MEMORY_SCOPE_AGENT);
    }
    if (threadIdx.x == 0) {
        while (__hip_atomic_load(gate, __ATOMIC_RELAXED, __HIP_MEMORY_SCOPE_AGENT) < epoch)
            __builtin_amdgcn_s_sleep(1);
    }
    __syncthreads();
    __builtin_amdgcn_fence(__ATOMIC_ACQUIRE, "agent");
}

// fallback-only counter exchange (proven R5/R7/R8)
__device__ __forceinline__ void arrive_cnt(unsigned* cnt) {
    __syncthreads();
    if (threadIdx.x == 0)
        __hip_atomic_fetch_add(cnt, 1u, __ATOMIC_RELEASE, __HIP_MEMORY_SCOPE_AGENT);
}
__device__ __forceinline__ void wait_cnt(unsigned* cnt, unsigned target) {
    if (threadIdx.x == 0) {
        while (__hip_atomic_load(cnt, __ATOMIC_RELAXED, __HIP_MEMORY_SCOPE_AGENT) < target)
            __builtin_amdgcn_s_sleep(2);
        __builtin_amdgcn_fence(__ATOMIC_ACQUIRE, "agent");
    }
    __syncthreads();
}

__global__ void __launch_bounds__(NTHR, 1)
epot_kernel(const float* __restrict__ C, const float* __restrict__ a,
            const float* __restrict__ b, float* __restrict__ K,
            Ws* __restrict__ ws)
{
    __shared__ _Float16 band[RPB][N];        // 32 KB fp16 K0 band (own rows)
    __shared__ double sUd[N];                // 16 KB full U table (redundant)
    __shared__ double s16[16];
    __shared__ double sredW[16][RPB][3];     // 3 KB wave partials (T,G,H)
    __shared__ double sColScr[3][RPB];
    __shared__ double sU[RPB], sUp[RPB], sRowPrev[RPB];
    __shared__ double sVown[RPB], sColPrev[RPB], sAn[RPB], sBn[RPB], sDot[RPB];

    const int tid = threadIdx.x, bid = blockIdx.x, lane = tid & 63;
    const int r0 = bid * RPB, rloc = tid >> 7, cgrp = tid & 127;

    // ---- P0: a/b sums (redundant), band = fp16(exp(-10C)), row/band/s2 sums ----
    const double a_sum = block_reduce((double)a[tid] + (double)a[tid + 1024], s16);
    const double b_sum = block_reduce((double)b[tid] + (double)b[tid + 1024], s16);
    {
        const int i = r0 + rloc;
        const float4* c4 = (const float4*)(C + (size_t)i * N);
        double s = 0.0, s2 = 0.0;
        #pragma unroll 4
        for (int j4 = cgrp; j4 < N / 4; j4 += 128) {
            float4 c = c4[j4];
            const float ex = expf(-10.0f * c.x), ey = expf(-10.0f * c.y);
            const float ez = expf(-10.0f * c.z), ew = expf(-10.0f * c.w);
            half4_t h; h[0] = (_Float16)ex; h[1] = (_Float16)ey;
                       h[2] = (_Float16)ez; h[3] = (_Float16)ew;
            *(half4_t*)&band[rloc][4 * j4] = h;
            s  += (double)ex + (double)ey + (double)ez + (double)ew;
            s2 += (double)ex * ex + (double)ey * ey + (double)ez * ez + (double)ew * ew;
        }
        for (int off = 32; off; off >>= 1) s += __shfl_xor(s, off, 64);
        __syncthreads();
        if (lane == 0) s16[tid >> 6] = s;    // 2 waves per row
        __syncthreads();
        if (tid < RPB) ws->rowSum[r0 + tid] = s16[2 * tid] + s16[2 * tid + 1];
        if (tid == 0) {
            double bs = 0.0;
            #pragma unroll
            for (int w = 0; w < 16; ++w) bs += s16[w];
            ws->bandSum[bid] = bs;
        }
        const double bs2 = block_reduce(s2, s16);
        if (tid == 0) ws->s2Band[bid] = bs2;
    }
    arrive_flag(&ws->flagS[bid], 1u);
    gate_rendezvous(ws->flagS, &ws->gateS, 1u);

    // ---- P1: W0, full U table (redundant), own 8 COLUMNS: T/G/H, V, dot/err ----
    const double k0sum = block_reduce((tid < NBLK) ? ws->bandSum[tid] : 0.0, s16);
    const double W0 = D_MASS / k0sum;
    {
        double u0 = ((double)a[tid] / a_sum) / (W0 * ws->rowSum[tid]);
        double u1 = ((double)a[tid + 1024] / a_sum) / (W0 * ws->rowSum[tid + 1024]);
        if (u0 > 1.0) u0 = 1.0;
        if (u1 > 1.0) u1 = 1.0;
        sUd[tid] = u0; sUd[tid + 1024] = u1;
    }
    __syncthreads();
    {
        const int c = tid & 7;               // column within block's 8
        const int jc = bid * RPB + c;
        const int m0 = tid >> 3;             // 0..127 row start
        double tA = 0.0, gA = 0.0, hA = 0.0;
        #pragma unroll 4
        for (int k = 0; k < 16; ++k) {
            const int i = m0 + 128 * k;
            const double e = (double)expf(-10.0f * C[(size_t)i * N + jc]);
            const double u = sUd[i];
            const double e2 = e * e;
            tA += u * e;
            gA += u * e2;
            hA += (u * u) * e2;
        }
        tA += __shfl_xor(tA, 8, 64); tA += __shfl_xor(tA, 16, 64); tA += __shfl_xor(tA, 32, 64);
        gA += __shfl_xor(gA, 8, 64); gA += __shfl_xor(gA, 16, 64); gA += __shfl_xor(gA, 32, 64);
        hA += __shfl_xor(hA, 8, 64); hA += __shfl_xor(hA, 16, 64); hA += __shfl_xor(hA, 32, 64);
        if (lane < RPB) {
            sredW[tid >> 6][lane][0] = tA;
            sredW[tid >> 6][lane][1] = gA;
            sredW[tid >> 6][lane][2] = hA;
        }
        __syncthreads();
        if (tid < RPB) {
            double T = 0.0, G = 0.0, H = 0.0;
            #pragma unroll
            for (int w = 0; w < 16; ++w) {
                T += sredW[w][tid][0]; G += sredW[w][tid][1]; H += sredW[w][tid][2];
            }
            const int j = bid * RPB + tid;
            double cf = ((double)b[j] / b_sum) / (W0 * T);
            if (cf > 1.0) cf = 1.0;
            ws->V[j] = (float)cf;
            sColScr[0][tid] = T * cf;
            sColScr[1][tid] = G * cf;
            sColScr[2][tid] = H * cf * cf;
        }
        __syncthreads();
        if (tid == 0) {
            double d = 0.0, ea = 0.0, eb = 0.0;
            #pragma unroll
            for (int q = 0; q < RPB; ++q) {
                d += sColScr[0][q]; ea += sColScr[1][q]; eb += sColScr[2][q];
            }
            ws->dotParts[bid] = d; ws->errAParts[bid] = ea; ws->errBParts[bid] = eb;
        }
    }
    arrive_flag(&ws->flagV[bid], 1u);
    gate_rendezvous(ws->flagV, &ws->gateV, 1u);

    // ---- P3: closed-form decision; fast path writes output, no further sync ----
    const double sd    = block_reduce((tid < NBLK) ? ws->dotParts[tid]  : 0.0, s16);
    const double errAs = block_reduce((tid < NBLK) ? ws->errAParts[tid] : 0.0, s16);
    const double errBs = block_reduce((tid < NBLK) ? ws->errBParts[tid] : 0.0, s16);
    const double s2tot = block_reduce((tid < NBLK) ? ws->s2Band[tid]    : 0.0, s16);
    const double Wn = D_MASS / sd;
    const double err2 = W0 * W0 * s2tot - 2.0 * W0 * Wn * errAs + Wn * Wn * errBs;

    if (sqrt(err2) <= D_TOL) {
        const int i = r0 + rloc;
        const double unw = Wn * sUd[i];
        const float4* vn4 = (const float4*)ws->V;
        float4* k4p = (float4*)(K + (size_t)i * N);
        #pragma unroll 4
        for (int j4 = cgrp; j4 < N / 4; j4 += 128) {
            half4_t h = *(const half4_t*)&band[rloc][4 * j4];
            float4 vn = vn4[j4];
            float4 kn;
            kn.x = (float)(unw * (double)(float)h[0] * (double)vn.x);
            kn.y = (float)(unw * (double)(float)h[1] * (double)vn.y);
            kn.z = (float)(unw * (double)(float)h[2] * (double)vn.z);
            kn.w = (float)(unw * (double)(float)h[3] * (double)vn.w);
            k4p[j4] = kn;
        }
        return;
    }

    // ---- fallback (never taken on converging data): iterate 1..49 ----
    if (tid < RPB) {
        sU[tid] = sUd[r0 + tid];
        sRowPrev[tid] = sU[tid];
        sVown[tid] = (double)ws->V[r0 + tid];
        sColPrev[tid] = sVown[tid];
        sAn[tid] = (double)a[r0 + tid] / a_sum;
        sBn[tid] = (double)b[r0 + tid] / b_sum;
        sUp[tid] = 1.0;
    }
    __syncthreads();

    double W = 0.0, Wp = 0.0;
    bool done = false;

    for (int cpt = 1; cpt < NITER && !done; ++cpt) {
        const bool erriter = (cpt % 10) == 0;

        if (cpt > 1) wait_cnt(&ws->cntV, (unsigned)(NBLK * (cpt - 1)));
        W = D_MASS / block_reduce((tid < NBLK) ? ws->dotParts[tid] : 0.0, s16);
        if (erriter) {
            Wp = W;
            if (tid < RPB) sUp[tid] = sU[tid];
        }
        __syncthreads();

        // A1: row sums (band x V) + row scaling
        {
            const float4* v4 = (const float4*)ws->V;
            double s = 0.0;
            #pragma unroll 4
            for (int j4 = cgrp; j4 < N / 4; j4 += 128) {
                half4_t h = *(const half4_t*)&band[rloc][4 * j4];
                float4 vv = v4[j4];
                s += (double)((float)h[0] * vv.x) + (double)((float)h[1] * vv.y)
                   + (double)((float)h[2] * vv.z) + (double)((float)h[3] * vv.w);
            }
            for (int off = 32; off; off >>= 1) s += __shfl_xor(s, off, 64);
            __syncthreads();
            if (lane == 0) s16[tid >> 6] = s;
            __syncthreads();
            if (tid < RPB) {
                const double Uq = sU[tid] / sRowPrev[tid];
                double r = sAn[tid] / (Uq * W * (s16[2 * tid] + s16[2 * tid + 1]));
                if (r > 1.0) r = 1.0;
                sU[tid] = Uq * r; sRowPrev[tid] = r;
            }
        }
        __syncthreads();

        // A2: column partials -> [col][srcblk]
        {
            double ub[RPB];
            #pragma unroll
            for (int r = 0; r < RPB; ++r) ub[r] = sU[r];
            const int j0 = 2 * tid;
            double ax = 0.0, ay = 0.0;
            #pragma unroll
            for (int r = 0; r < RPB; ++r) {
                half2_t hv = *(const half2_t*)&band[r][j0];
                ax += (double)(float)hv[0] * ub[r];
                ay += (double)(float)hv[1] * ub[r];
            }
            ws->partialT[(size_t)j0 * NBLK + bid]       = (float)ax;
            ws->partialT[(size_t)(j0 + 1) * NBLK + bid] = (float)ay;
        }
        arrive_cnt(&ws->cntP);
        wait_cnt(&ws->cntP, (unsigned)(NBLK * cpt));

        // B: own 8 columns (coalesced), col scaling, V, dot partial
        {
            const int jj = tid >> 7, p = tid & 127;
            const int j = r0 + jj;
            double t = (double)ws->partialT[(size_t)j * NBLK + p]
                     + (double)ws->partialT[(size_t)j * NBLK + 128 + p];
            for (int off = 32; off; off >>= 1) t += __shfl_xor(t, off, 64);
            __syncthreads();
            if (lane == 0) s16[tid >> 6] = t;
            __syncthreads();
            if (tid < RPB) {
                const double Tj = s16[2 * tid] + s16[2 * tid + 1];
                const double Vq = sVown[tid] / sColPrev[tid];
                double cf = sBn[tid] / (Vq * W * Tj);
                if (cf > 1.0) cf = 1.0;
                if (erriter) ws->Vp[r0 + tid] = (float)sVown[tid];
                const double Vn = Vq * cf;
                sVown[tid] = Vn; sColPrev[tid] = cf;
                ws->V[r0 + tid] = (float)Vn;
                sDot[tid] = Tj * Vn;
            }
            __syncthreads();
            if (tid == 0) {
                double d = 0.0;
                #pragma unroll
                for (int q = 0; q < RPB; ++q) d += sDot[q];
                ws->dotParts[bid] = d;
            }
        }
        arrive_cnt(&ws->cntV);

        // err check + speculative output (every 10 iters)
        if (erriter) {
            wait_cnt(&ws->cntV, (unsigned)(NBLK * cpt));
            const double sdl = block_reduce((tid < NBLK) ? ws->dotParts[tid] : 0.0, s16);
            const double Wc = D_MASS / sdl;
            const int i = r0 + rloc;
            const double upw = sUp[rloc] * Wp;
            const double unw = sU[rloc] * Wc;
            const float4* vp4 = (const float4*)ws->Vp;
            const float4* vn4 = (const float4*)ws->V;
            float4* k4p = (float4*)(K + (size_t)i * N);
            double e2 = 0.0;
            #pragma unroll 4
            for (int j4 = cgrp; j4 < N / 4; j4 += 128) {
                half4_t h = *(const half4_t*)&band[rloc][4 * j4];
                float4 vp = vp4[j4], vn = vn4[j4];
                double d;
                d = (double)(float)h[0] * (upw * (double)vp.x - unw * (double)vn.x); e2 += d * d;
                d = (double)(float)h[1] * (upw * (double)vp.y - unw * (double)vn.y); e2 += d * d;
                d = (double)(float)h[2] * (upw * (double)vp.z - unw * (double)vn.z); e2 += d * d;
                d = (double)(float)h[3] * (upw * (double)vp.w - unw * (double)vn.w); e2 += d * d;
            }
            const double be = block_reduce(e2, s16);
            if (tid == 0) ws->errParts[bid] = be;
            arrive_cnt(&ws->cntE);
            #pragma unroll 4
            for (int j4 = cgrp; j4 < N / 4; j4 += 128) {
                half4_t h = *(const half4_t*)&band[rloc][4 * j4];
                float4 vn = vn4[j4];
                float4 kn;
                kn.x = (float)(unw * (double)(float)h[0] * (double)vn.x);
                kn.y = (float)(unw * (double)(float)h[1] * (double)vn.y);
                kn.z = (float)(unw * (double)(float)h[2] * (double)vn.z);
                kn.w = (float)(unw * (double)(float)h[3] * (double)vn.w);
                k4p[j4] = kn;
            }
            wait_cnt(&ws->cntE, (unsigned)(NBLK * (cpt / 10)));
            const double te = block_reduce((tid < NBLK) ? ws->errParts[tid] : 0.0, s16);
            done = (sqrt(te) <= D_TOL);
        }
    }

    if (!done) {
        wait_cnt(&ws->cntV, (unsigned)(NBLK * (NITER - 1)));
        const double sdl = block_reduce((tid < NBLK) ? ws->dotParts[tid] : 0.0, s16);
        const double Wf = D_MASS / sdl;
        const int i = r0 + rloc;
        const double uf = sU[rloc] * Wf;
        const float4* vn4 = (const float4*)ws->V;
        float4* k4p = (float4*)(K + (size_t)i * N);
        #pragma unroll 4
        for (int j4 = cgrp; j4 < N / 4; j4 += 128) {
            half4_t h = *(const half4_t*)&band[rloc][4 * j4];
            float4 vv = vn4[j4];
            float4 o;
            o.x = (float)(uf * (double)(float)h[0] * (double)vv.x);
            o.y = (float)(uf * (double)(float)h[1] * (double)vv.y);
            o.z = (float)(uf * (double)(float)h[2] * (double)vv.z);
            o.w = (float)(uf * (double)(float)h[3] * (double)vv.w);
            k4p[j4] = o;
        }
    }
}

extern "C" void kernel_launch(void* const* d_in, const int* in_sizes, int n_in,
                              void* d_out, int out_size, void* d_ws, size_t ws_size,
                              hipStream_t stream) {
    const float* C = (const float*)d_in[0];
    const float* a = (const float*)d_in[1];
    const float* b = (const float*)d_in[2];
    float* K = (float*)d_out;
    Ws*    w = (Ws*)d_ws;

    init_sync<<<1, NBLK, 0, stream>>>(w);
    void* args[5] = { (void*)&C, (void*)&a, (void*)&b, (void*)&K, (void*)&w };
    (void)hipLaunchCooperativeKernel((const void*)epot_kernel, dim3(NBLK), dim3(NTHR),
                                     args, 0, stream);
}

// Round 10
// 33.792 us; speedup vs baseline: 4.0094x; 4.0094x over previous
//
#include <hip/hip_runtime.h>

static constexpr int    N      = 2048;
static constexpr int    NBLK   = 256;
static constexpr int    NTHR   = 1024;
static constexpr int    RPB    = 8;     // rows (or cols) per block
static constexpr double D_MASS = 0.9;
static constexpr double D_TOL  = 0.01;
static constexpr int    NITER  = 50;

struct Ws {
    double a_sum, b_sum;
    double bandSum[NBLK];
    double rowSum[N];
    double dotParts[NBLK];
    double errParts[NBLK];
    float  U[N], V[N];
    // fallback-only double state (single-block path; never touched on fast path)
    double Ud[N], rpD[N], Vd[N], cpD[N], UpD[N], VpD[N];
    float  partialT[(size_t)N * NBLK];   // [col][srcblk], 2 MB
};

// deterministic all-thread block reduction (1024 threads, 16 waves)
__device__ __forceinline__ double block_reduce(double v, double* s16) {
    for (int off = 32; off; off >>= 1) v += __shfl_xor(v, off, 64);
    const int wave = threadIdx.x >> 6, lane = threadIdx.x & 63;
    __syncthreads();
    if (lane == 0) s16[wave] = v;
    __syncthreads();
    double s = 0.0;
    #pragma unroll
    for (int w = 0; w < 16; ++w) s += s16[w];
    return s;
}

// ---- K1: row sums + band sums of K0 = exp(-10C), a/b sums ----
__global__ void __launch_bounds__(NTHR)
k1_sums(const float* __restrict__ C, const float* __restrict__ a,
        const float* __restrict__ b, Ws* __restrict__ ws)
{
    __shared__ double s16[16];
    const int tid = threadIdx.x, bid = blockIdx.x, lane = tid & 63;
    const int r0 = bid * RPB, rloc = tid >> 7, cgrp = tid & 127;

    if (bid == 0) {
        double t = block_reduce((double)a[tid] + (double)a[tid + 1024], s16);
        if (tid == 0) ws->a_sum = t;
    } else if (bid == 1) {
        double t = block_reduce((double)b[tid] + (double)b[tid + 1024], s16);
        if (tid == 0) ws->b_sum = t;
    }

    const int i = r0 + rloc;
    const float4* c4 = (const float4*)(C + (size_t)i * N);
    double s = 0.0;
    #pragma unroll 4
    for (int j4 = cgrp; j4 < N / 4; j4 += 128) {
        float4 c = c4[j4];
        s += (double)expf(-10.0f * c.x) + (double)expf(-10.0f * c.y)
           + (double)expf(-10.0f * c.z) + (double)expf(-10.0f * c.w);
    }
    for (int off = 32; off; off >>= 1) s += __shfl_xor(s, off, 64);
    __syncthreads();                     // s16 free (block_reduce readers done)
    if (lane == 0) s16[tid >> 6] = s;    // 2 waves per row
    __syncthreads();
    if (tid < RPB) ws->rowSum[r0 + tid] = s16[2 * tid] + s16[2 * tid + 1];
    if (tid == 0) {
        double bs = 0.0;
        #pragma unroll
        for (int w = 0; w < 16; ++w) bs += s16[w];
        ws->bandSum[bid] = bs;
    }
}

// ---- K2: iter-0 row scaling (U), column partials [col][srcblk] ----
__global__ void __launch_bounds__(NTHR)
k2_rowscale_colpart(const float* __restrict__ C, const float* __restrict__ a,
                    Ws* __restrict__ ws)
{
    __shared__ double s16[16];
    __shared__ double sU[RPB];
    const int tid = threadIdx.x, bid = blockIdx.x;
    const int r0 = bid * RPB;

    const double k0sum = block_reduce((tid < NBLK) ? ws->bandSum[tid] : 0.0, s16);
    const double W0 = D_MASS / k0sum;

    if (tid < RPB) {
        const int i = r0 + tid;
        double r = ((double)a[i] / ws->a_sum) / (W0 * ws->rowSum[i]);
        if (r > 1.0) r = 1.0;
        sU[tid] = r;
        ws->U[i] = (float)r;
    }
    __syncthreads();

    double ub[RPB];
    #pragma unroll
    for (int r = 0; r < RPB; ++r) ub[r] = sU[r];
    const int j0 = 2 * tid;
    double ax = 0.0, ay = 0.0;
    #pragma unroll
    for (int r = 0; r < RPB; ++r) {
        const float2 c = *(const float2*)(C + (size_t)(r0 + r) * N + j0);
        ax += (double)expf(-10.0f * c.x) * ub[r];
        ay += (double)expf(-10.0f * c.y) * ub[r];
    }
    ws->partialT[(size_t)j0 * NBLK + bid]       = (float)ax;
    ws->partialT[(size_t)(j0 + 1) * NBLK + bid] = (float)ay;
}

// ---- K3: column reduce (coalesced), col scaling, V, dot partials ----
__global__ void __launch_bounds__(256)
k3_colscale(const float* __restrict__ b, Ws* __restrict__ ws)
{
    __shared__ double s4[4];
    __shared__ double sT[RPB], sD[RPB];
    const int tid = threadIdx.x, bid = blockIdx.x;

    double v = (double)ws->bandSum[tid];     // 256 values, one per thread
    for (int off = 32; off; off >>= 1) v += __shfl_xor(v, off, 64);
    if ((tid & 63) == 0) s4[tid >> 6] = v;
    __syncthreads();
    const double W0 = D_MASS / (s4[0] + s4[1] + s4[2] + s4[3]);

    const int jj = tid >> 5, p = tid & 31;   // 32 threads per column
    const int j = bid * RPB + jj;
    double t = 0.0;
    #pragma unroll
    for (int q = 0; q < 8; ++q)
        t += (double)ws->partialT[(size_t)j * NBLK + p + 32 * q];
    for (int off = 16; off; off >>= 1) t += __shfl_xor(t, off, 64);
    if (p == 0) sT[jj] = t;
    __syncthreads();

    if (tid < RPB) {
        const int jc = bid * RPB + tid;
        const double Tj = sT[tid];
        double cf = ((double)b[jc] / ws->b_sum) / (W0 * Tj);   // Vq = 1
        if (cf > 1.0) cf = 1.0;
        ws->V[jc] = (float)cf;
        sD[tid] = Tj * cf;
    }
    __syncthreads();
    if (tid == 0) {
        double d = 0.0;
        #pragma unroll
        for (int q = 0; q < RPB; ++q) d += sD[q];
        ws->dotParts[bid] = d;
    }
}

// ---- K4: Wn, fused err^2 partials + speculative output (fp32 exp) ----
__global__ void __launch_bounds__(NTHR)
k4_err_out(const float* __restrict__ C, float* __restrict__ K, Ws* __restrict__ ws)
{
    __shared__ double s16[16];
    const int tid = threadIdx.x, bid = blockIdx.x;
    const int r0 = bid * RPB, rloc = tid >> 7, cgrp = tid & 127;

    const double sd = block_reduce((tid < NBLK) ? ws->dotParts[tid] : 0.0, s16);
    const double Wn = D_MASS / sd;
    const double k0sum = block_reduce((tid < NBLK) ? ws->bandSum[tid] : 0.0, s16);
    const double upw = D_MASS / k0sum;       // Kprev = W0*K0 (U_prev=V_prev=1)

    const int i = r0 + rloc;
    const double unw = Wn * (double)ws->U[i];
    const float4* c4  = (const float4*)(C + (size_t)i * N);
    const float4* vn4 = (const float4*)ws->V;
    float4* k4p = (float4*)(K + (size_t)i * N);
    double e2 = 0.0;
    #pragma unroll 4
    for (int j4 = cgrp; j4 < N / 4; j4 += 128) {
        float4 c = c4[j4], vn = vn4[j4];
        const double k0x = (double)expf(-10.0f * c.x);
        const double k0y = (double)expf(-10.0f * c.y);
        const double k0z = (double)expf(-10.0f * c.z);
        const double k0w = (double)expf(-10.0f * c.w);
        float4 kn;
        kn.x = (float)(unw * k0x * (double)vn.x);
        kn.y = (float)(unw * k0y * (double)vn.y);
        kn.z = (float)(unw * k0z * (double)vn.z);
        kn.w = (float)(unw * k0w * (double)vn.w);
        k4p[j4] = kn;                        // speculative final output (iter-0 Kn)
        double d;
        d = k0x * (upw - unw * (double)vn.x); e2 += d * d;
        d = k0y * (upw - unw * (double)vn.y); e2 += d * d;
        d = k0z * (upw - unw * (double)vn.z); e2 += d * d;
        d = k0w * (upw - unw * (double)vn.w); e2 += d * d;
    }
    const double be = block_reduce(e2, s16);
    if (tid == 0) ws->errParts[bid] = be;
}

// ---- K5: single block, regular launch. Converged -> exit (~2 us).
//      Not converged (never on this data): serial faithful iterations. ----
__global__ void __launch_bounds__(NTHR)
k5_decide_fallback(const float* __restrict__ C, const float* __restrict__ a,
                   const float* __restrict__ b, float* __restrict__ K,
                   Ws* __restrict__ ws)
{
    __shared__ double s16[16];
    const int tid = threadIdx.x;

    const double te0 = block_reduce((tid < NBLK) ? ws->errParts[tid] : 0.0, s16);
    if (sqrt(te0) <= D_TOL) return;          // fast path: K4's output stands

    // ======== fallback: one block runs the exact algorithm serially ========
    const double a_sum = ws->a_sum, b_sum = ws->b_sum;
    const double sd0 = block_reduce((tid < NBLK) ? ws->dotParts[tid] : 0.0, s16);
    double W = D_MASS / sd0;                 // state after iter 0 mass scale

    for (int i = tid; i < N; i += NTHR) {    // seed state from iter 0
        ws->Ud[i]  = (double)ws->U[i];
        ws->rpD[i] = ws->Ud[i];              // row_prev = r (Uq was 1)
        ws->Vd[i]  = (double)ws->V[i];
        ws->cpD[i] = ws->Vd[i];
        ws->UpD[i] = 1.0; ws->VpD[i] = 1.0;
    }
    __syncthreads();

    double Wp = 0.0;
    bool done = false;
    for (int cpt = 1; cpt < NITER && !done; ++cpt) {
        const bool erriter = (cpt % 10) == 0;
        if (erriter) {
            Wp = W;
            for (int i = tid; i < N; i += NTHR) {
                ws->UpD[i] = ws->Ud[i]; ws->VpD[i] = ws->Vd[i];
            }
        }
        __syncthreads();

        // row scaling
        for (int i = tid; i < N; i += NTHR) {
            const float* crow = C + (size_t)i * N;
            double s = 0.0;
            for (int j = 0; j < N; ++j)
                s += (double)expf(-10.0f * crow[j]) * ws->Vd[j];
            const double Uq = ws->Ud[i] / ws->rpD[i];
            double r = ((double)a[i] / a_sum) / (Uq * W * s);
            if (r > 1.0) r = 1.0;
            ws->Ud[i] = Uq * r; ws->rpD[i] = r;
        }
        __syncthreads();

        // col scaling + dot
        double dloc = 0.0;
        for (int j = tid; j < N; j += NTHR) {
            double t = 0.0;
            for (int i = 0; i < N; ++i)
                t += (double)expf(-10.0f * C[(size_t)i * N + j]) * ws->Ud[i];
            const double Vq = ws->Vd[j] / ws->cpD[j];
            double cf = ((double)b[j] / b_sum) / (Vq * W * t);
            if (cf > 1.0) cf = 1.0;
            const double Vn = Vq * cf;
            ws->Vd[j] = Vn; ws->cpD[j] = cf;
            dloc += t * Vn;
        }
        const double sd = block_reduce(dloc, s16);
        W = D_MASS / sd;                     // post-mass-scale W of this iter

        if (erriter) {
            double e2 = 0.0;
            for (int i = tid; i < N; i += NTHR) {
                const float* crow = C + (size_t)i * N;
                const double up = Wp * ws->UpD[i];
                const double un = W  * ws->Ud[i];
                for (int j = 0; j < N; ++j) {
                    const double k0 = (double)expf(-10.0f * crow[j]);
                    const double d = k0 * (up * ws->VpD[j] - un * ws->Vd[j]);
                    e2 += d * d;
                }
            }
            const double te = block_reduce(e2, s16);
            done = (sqrt(te) <= D_TOL);
        }
        __syncthreads();
    }

    // final output from current state
    for (int i = tid; i < N; i += NTHR) {
        const float* crow = C + (size_t)i * N;
        float* krow = K + (size_t)i * N;
        const double uw = W * ws->Ud[i];
        for (int j = 0; j < N; ++j)
            krow[j] = (float)(uw * (double)expf(-10.0f * crow[j]) * ws->Vd[j]);
    }
}

extern "C" void kernel_launch(void* const* d_in, const int* in_sizes, int n_in,
                              void* d_out, int out_size, void* d_ws, size_t ws_size,
                              hipStream_t stream) {
    const float* C = (const float*)d_in[0];
    const float* a = (const float*)d_in[1];
    const float* b = (const float*)d_in[2];
    float* K = (float*)d_out;
    Ws*    w = (Ws*)d_ws;

    k1_sums<<<NBLK, NTHR, 0, stream>>>(C, a, b, w);
    k2_rowscale_colpart<<<NBLK, NTHR, 0, stream>>>(C, a, w);
    k3_colscale<<<NBLK, 256, 0, stream>>>(b, w);
    k4_err_out<<<NBLK, NTHR, 0, stream>>>(C, K, w);
    k5_decide_fallback<<<1, NTHR, 0, stream>>>(C, a, b, K, w);
}